// Round 18
// baseline (236.346 us; speedup 1.0000x reference)
//
#include <hip/hip_runtime.h>
#include <hip/hip_bf16.h>

#define Lc 4
#define Nc 50000
#define Ec 800000
#define Bc 16384
#define EDc 256
#define Kc 7
#define Mtot (Lc * Nc)      // 200000 nodes total
#define KDIM (EDc * Kc)     // 1792

#define BINW 512            // nodes per bin
#define BSH 9
#define FB 98               // bins per layer = ceil(50000/512)
#define NBINS (FB * Lc)     // 392
#define CAPc 12288          // csr capacity per bin (mean 8192)
#define CHUNK 8192          // edges per binfill block
#define FBLK 98             // ceil(Ec/CHUNK)
#define SCAP 160            // slots per (block,bin) cell: mean 84 + 8.4 sigma

#define PADTOT 33024        // 32768 sides + per-layer pad to 64
#define PADBIT (1 << 24)

typedef __attribute__((ext_vector_type(8))) short bf16x8;
typedef __attribute__((ext_vector_type(4))) float f32x4;

static __device__ __forceinline__ unsigned short f2bf(float f) {
    unsigned u = __float_as_uint(f);
    unsigned r = (u + 0x7fffu + ((u >> 16) & 1u)) >> 16;
    return (unsigned short)r;
}
static __device__ __forceinline__ float bf2f(unsigned short u) {
    return __uint_as_float(((unsigned)u) << 16);
}

// ---------------- prep: weight transposes + scratch zero -------------------

__global__ void k_prep(const float* __restrict__ conv_w, unsigned short* __restrict__ wbt,
                       const float* __restrict__ W2, unsigned short* __restrict__ w2t,
                       int* __restrict__ zeroRegion, int zn) {
    int bb = blockIdx.x;
    if (bb < 1792) {
        int i = bb * 256 + threadIdx.x;       // 458752
        int co = i / KDIM;
        int r = i % KDIM;
        int ci = r / Kc, k = r % Kc;
        wbt[(size_t)co * KDIM + k * EDc + ci] = f2bf(conv_w[i]);
    } else {
        int i = (bb - 1792) * 256 + threadIdx.x;  // 0..32767
        if (i < zn) zeroRegion[i] = 0;
        int l = i >> 13, r = i & 8191;
        int d = r >> 6, h = r & 63;
        w2t[i] = f2bf(W2[(size_t)(l * 64 + h) * 128 + d]);
    }
}

// mark sampled (layer,node) bitmap + per-layer sample counts + init ord
__global__ void k_mark(const int* __restrict__ now, const int* __restrict__ lnn,
                       const int* __restrict__ rnn, int* __restrict__ ord,
                       unsigned* __restrict__ bitmap, int* __restrict__ gcnt) {
    int b = blockIdx.x * 256 + threadIdx.x;   // exactly 16384 threads
    for (int p = b; p < PADTOT; p += 16384) ord[p] = PADBIT;
    int l = now[b];
    int a1 = l * Nc + lnn[b];
    atomicOr(&bitmap[a1 >> 5], 1u << (a1 & 31));
    int a2 = l * Nc + rnn[b];
    atomicOr(&bitmap[a2 >> 5], 1u << (a2 & 31));
    int lane = threadIdx.x & 63;
#pragma unroll
    for (int ll = 0; ll < 4; ll++) {
        unsigned long long m = __ballot(l == ll);
        if (m && lane == __builtin_ctzll(m)) atomicAdd(&gcnt[ll], __popcll(m));
    }
}

// ---------------- single-pass binned edge sort -----------------------------

__global__ __launch_bounds__(512) void k_binfill(const int* __restrict__ ei,
                                                 int* __restrict__ blkCnt,
                                                 int* __restrict__ binned) {
    int l = blockIdx.y, bx = blockIdx.x;
    int e0 = bx * CHUNK;
    __shared__ int lcur[FB];
    if (threadIdx.x < FB) lcur[threadIdx.x] = 0;
    __syncthreads();
    const int* srcp = ei + (size_t)l * 2 * Ec;
    const int* dstp = srcp + Ec;
    int segBase = (l * FBLK + bx) * FB;
#pragma unroll
    for (int it = 0; it < CHUNK / 512; it++) {
        int idx = e0 + it * 512 + threadIdx.x;
        if (idx < Ec) {
            int d = dstp[idx], sv = srcp[idx];
            int t = d >> BSH;
            int slot = atomicAdd(&lcur[t], 1);
            if (slot < SCAP)
                binned[(size_t)(segBase + t) * SCAP + slot] = (sv << BSH) | (d & (BINW - 1));
        }
    }
    __syncthreads();
    if (threadIdx.x < FB) blkCnt[segBase + threadIdx.x] = min(lcur[threadIdx.x], SCAP);
}

// one block per bin: hist + rstart/cnt/dis/g + bitmap-filtered csr scatter
__global__ __launch_bounds__(512) void k_csr(const int* __restrict__ blkCnt,
                                             const int* __restrict__ binned,
                                             const float* __restrict__ x_nodes,
                                             const unsigned* __restrict__ bitmap,
                                             int* __restrict__ csr,
                                             int* __restrict__ rstart,
                                             int* __restrict__ cnt,
                                             float* __restrict__ dis,
                                             float* __restrict__ g) {
    int b = blockIdx.x;              // 0..NBINS-1
    int l = b / FB, gg = b % FB;
    int rs = b * CAPc;
    __shared__ int segc[FBLK];
    __shared__ int hist[BINW];
    if (threadIdx.x < FBLK) segc[threadIdx.x] = blkCnt[(l * FBLK + threadIdx.x) * FB + gg];
    hist[threadIdx.x] = 0;
    __syncthreads();
    const int PADN = FBLK * SCAP;    // 15680
    size_t binBase = (size_t)l * FBLK * FB + gg;
    for (int i = threadIdx.x; i < PADN; i += 512) {
        int seg = i / SCAP, sl = i - seg * SCAP;
        if (sl < segc[seg]) {
            int p = binned[(binBase + (size_t)seg * FB) * SCAP + sl];
            atomicAdd(&hist[p & (BINW - 1)], 1);
        }
    }
    __syncthreads();
    int lane = threadIdx.x & 63, wid = threadIdx.x >> 6;
    int v = hist[threadIdx.x];
    int x = v;
#pragma unroll
    for (int off = 1; off < 64; off <<= 1) {
        int y = __shfl_up(x, off);
        if (lane >= off) x += y;
    }
    __shared__ int ws[8];
    if (lane == 63) ws[wid] = x;
    __syncthreads();
    int carry = 0;
    for (int w = 0; w < wid; w++) carry += ws[w];
    int exc = x - v + carry;         // exclusive prefix within bin
    int n = gg * BINW + threadIdx.x;
    int n4 = l * Nc + n;
    if (n < Nc) {
        rstart[n4] = rs + exc;
        cnt[n4] = v;
        float dn = rsqrtf((float)v + 1.0f);   // +1 self loop
        dis[n4] = dn;
        g[n4] = dn * x_nodes[(size_t)l * Nc + n];
    }
    __syncthreads();                 // all reads of hist done
    hist[threadIdx.x] = rs + exc;    // reuse as cursor
    __syncthreads();
    int lbase = l * Nc + gg * BINW;
    for (int i = threadIdx.x; i < PADN; i += 512) {
        int seg = i / SCAP, sl = i - seg * SCAP;
        if (sl < segc[seg]) {
            unsigned p = (unsigned)binned[(binBase + (size_t)seg * FB) * SCAP + sl];
            int d = p & (BINW - 1);
            int nn4 = lbase + d;
            if ((bitmap[nn4 >> 5] >> (nn4 & 31)) & 1u) {   // only sampled dst rows
                int pos = atomicAdd(&hist[d], 1);
                csr[pos] = (int)(p >> BSH);
            }
        }
    }
}

// edge-parallel s aggregation + BN stats (per bin); packs ns = (dis, s)
__global__ __launch_bounds__(512) void k_s_bin(const int* __restrict__ blkCnt,
                                               const int* __restrict__ binned,
                                               const float* __restrict__ g,
                                               const float* __restrict__ dis,
                                               float2* __restrict__ ns,
                                               double* __restrict__ stats) {
    int b = blockIdx.x;              // 0..NBINS-1
    int l = b / FB, gg = b % FB;
    const float* gl = g + (size_t)l * Nc;
    __shared__ int segc[FBLK];
    __shared__ float acc[BINW];
    if (threadIdx.x < FBLK) segc[threadIdx.x] = blkCnt[(l * FBLK + threadIdx.x) * FB + gg];
    acc[threadIdx.x] = 0.f;
    __syncthreads();
    const int PADN = FBLK * SCAP;
    size_t binBase = (size_t)l * FBLK * FB + gg;
    for (int i = threadIdx.x; i < PADN; i += 512) {
        int seg = i / SCAP, sl = i - seg * SCAP;
        if (sl < segc[seg]) {
            unsigned p = (unsigned)binned[(binBase + (size_t)seg * FB) * SCAP + sl];
            atomicAdd(&acc[p & (BINW - 1)], gl[p >> BSH]);   // LDS fp32 atomic
        }
    }
    __syncthreads();
    int n = gg * BINW + threadIdx.x;
    int n4 = l * Nc + n;
    double v = 0.0, v2 = 0.0;
    if (n < Nc) {
        float dn = dis[n4];
        float sf = dn * (acc[threadIdx.x] + g[n4]);  // neighbors + self loop
        ns[n4] = make_float2(dn, sf);
        v = (double)sf;
        v2 = (double)sf * (double)sf;
    }
    for (int m = 32; m; m >>= 1) { v += __shfl_xor(v, m); v2 += __shfl_xor(v2, m); }
    __shared__ double r0[8], r1[8];
    int wid = threadIdx.x >> 6, lane = threadIdx.x & 63;
    if (lane == 0) { r0[wid] = v; r1[wid] = v2; }
    __syncthreads();
    if (threadIdx.x == 0) {
        double a = 0, bb = 0;
        for (int w = 0; w < 8; w++) { a += r0[w]; bb += r1[w]; }
        atomicAdd(&stats[l * 2 + 0], a);
        atomicAdd(&stats[l * 2 + 1], bb);
    }
}

// ---------------- side ordering + BN coefficient vector (fused) ------------

__global__ __launch_bounds__(256) void k_ordcvec(const int* __restrict__ now,
        const int* __restrict__ gcnt, int* __restrict__ gcur, int* __restrict__ ord,
        const double* __restrict__ stats, const float* __restrict__ W1,
        const float* __restrict__ gamma, float* __restrict__ cbuf) {
    if (blockIdx.x == 64) {          // cvec block
        int l = threadIdx.x >> 6, h = threadIdx.x & 63;
        double mean = stats[l * 2] / (double)Nc;
        double var = stats[l * 2 + 1] / (double)Nc - mean * mean;
        float w = W1[l * 64 + h];
        cbuf[l * 72 + h] = gamma[l * 64 + h] * w * rsqrtf((float)var * w * w + 1e-5f);
        if (h == 0) cbuf[l * 72 + 64] = (float)mean;
        return;
    }
    int b = blockIdx.x * 256 + threadIdx.x;   // exactly 16384
    int l = now[b];
    int segBase = 0;
    for (int ll = 0; ll < l; ll++) segBase += (2 * gcnt[ll] + 63) & ~63;
    int lane = threadIdx.x & 63;
#pragma unroll
    for (int ll = 0; ll < 4; ll++) {
        unsigned long long m = __ballot(l == ll);
        if (!m) continue;
        int ldr = __builtin_ctzll(m);
        int bs = 0;
        if (lane == ldr) bs = atomicAdd(&gcur[ll], __popcll(m));
        bs = __shfl(bs, ldr);
        if (l == ll) {
            int rk = __popcll(m & (lane ? ((1ull << lane) - 1) : 0ull));
            int sp = segBase + 2 * (bs + rk);
            ord[sp] = (2 * b) | (ll << 20);
            ord[sp + 1] = (2 * b + 1) | (ll << 20);
        }
    }
}

// ---------------- per-side aggregation (lane-parallel edge gather) ---------

__global__ __launch_bounds__(256) void k_agg(const int* __restrict__ ord,
        const int* __restrict__ lnn, const int* __restrict__ rnn,
        const int* __restrict__ rstart, const int* __restrict__ cnt,
        const int* __restrict__ csr, const float2* __restrict__ ns,
        const float* __restrict__ cbuf, const float* __restrict__ beta,
        unsigned short* __restrict__ acch) {
    int pos = blockIdx.x * 4 + (threadIdx.x >> 6);
    int lane = threadIdx.x & 63;
    int ordv = ord[pos];
    if (ordv & PADBIT) { acch[(size_t)pos * 64 + lane] = 0; return; }
    int side = ordv & 0xFFFFF;
    int l = (ordv >> 20) & 3;
    int b = side >> 1;
    int n = (side & 1) ? rnn[b] : lnn[b];
    int n4 = l * Nc + n;
    float c = cbuf[l * 72 + lane], mu = cbuf[l * 72 + 64], bt = beta[l * 64 + lane];
    const float2* nsl = ns + (size_t)l * Nc;
    int st = rstart[n4], deg = cnt[n4];
    float a = 0.f;
    for (int base = 0; base < deg; base += 64) {
        int e = base + lane;
        int sv = (e < deg) ? csr[st + e] : 0;        // coalesced vector load
        float nv = 0.f, fv = 0.f;
        if (e < deg) {
            float2 nf = nsl[sv];                     // 64 parallel gathers
            nv = nf.x; fv = nf.y;
        }
        int m = min(64, deg - base);
        for (int j = 0; j < m; j++) {
            float nj = __shfl(nv, j);
            float fj = __shfl(fv, j);
            a += nj * fmaxf(c * (fj - mu) + bt, 0.f);
        }
    }
    float2 nself = ns[n4];
    float hs = fmaxf(c * (nself.y - mu) + bt, 0.f);
    a = nself.x * a + nself.x * nself.x * hs;
    acch[(size_t)pos * 64 + lane] = f2bf(a);
}

// batched MFMA GEMM: [PADTOT x 64] @ W2[l][64 x 128] -> lsh (bf16)
__global__ __launch_bounds__(256) void k_embgemm(const unsigned short* __restrict__ acch,
        const int* __restrict__ ord, const unsigned short* __restrict__ w2t,
        const float* __restrict__ b2, unsigned short* __restrict__ lsh) {
    int t0 = blockIdx.x * 16;
    int wn = threadIdx.x >> 6, lane = threadIdx.x & 63;
    int lrow = lane & 15, lg = lane >> 4;
    int l = (ord[t0] >> 20) & 3;     // uniform layer for all valid rows in tile
    const unsigned short* ap = acch + (size_t)(t0 + lrow) * 64 + lg * 8;
    const unsigned short* bp = w2t + (size_t)(l * 128 + wn * 32 + lrow) * 64 + lg * 8;
    f32x4 acc[2] = {};
#pragma unroll
    for (int kt = 0; kt < 2; kt++) {
        bf16x8 a = *(const bf16x8*)(ap + kt * 32);
        bf16x8 b0 = *(const bf16x8*)(bp + kt * 32);
        bf16x8 b1 = *(const bf16x8*)(bp + 16 * 64 + kt * 32);
        acc[0] = __builtin_amdgcn_mfma_f32_16x16x32_bf16(a, b0, acc[0], 0, 0, 0);
        acc[1] = __builtin_amdgcn_mfma_f32_16x16x32_bf16(a, b1, acc[1], 0, 0, 0);
    }
#pragma unroll
    for (int r = 0; r < 4; r++) {
        int pos = t0 + lg * 4 + r;
        int ordv = ord[pos];
        if (ordv & PADBIT) continue;
        int side = ordv & 0xFFFFF;
        size_t base = (size_t)(side >> 1) * 256 + (side & 1) * 128;
#pragma unroll
        for (int ni = 0; ni < 2; ni++) {
            int n = wn * 32 + ni * 16 + lrow;
            lsh[base + n] = f2bf(acc[ni][r] + b2[l * 128 + n]);
        }
    }
}

// ---------------- fused conv1d MFMA GEMM + ortho/link/disc epilogue --------
// M-tile 32 (grid 512 = 2 blocks/CU; round-17 lesson: the 256-block grid
// itself capped occupancy at 8 waves/CU). Wave = 32 rows x 32 co, B buffer
// 16 x bf16x8 (small enough to stay in registers; VGPR<=128 via
// __launch_bounds__(512,4)), sched_barrier pins prefetch above MFMA burst.

__global__ __launch_bounds__(512, 4) void k_convfinal(const unsigned short* __restrict__ lsh,
        const unsigned short* __restrict__ wbt, const float* __restrict__ cb,
        const float* __restrict__ lc_w, const float* __restrict__ lc_b,
        const float* __restrict__ link_w, const float* __restrict__ link_b,
        float* __restrict__ out) {
    __shared__ unsigned short lsa[38 * EDc];   // 19456 B (bf16 ls window)
    __shared__ float shs[32][258];             // 33024 B (f32 shared rows, padded)
    int b0 = blockIdx.x * 32;
    int wid = threadIdx.x >> 6, lane = threadIdx.x & 63;
    int lrow = lane & 15, lg = lane >> 4;

    for (int idx = threadIdx.x; idx < 38 * 32; idx += 512) {
        int r = idx >> 5, c = idx & 31;
        int grow = b0 - 3 + r;
        uint4 v = make_uint4(0u, 0u, 0u, 0u);
        if ((unsigned)grow < (unsigned)Bc)
            v = *(const uint4*)(lsh + (size_t)grow * EDc + c * 8);
        int byte = (r * 512 + c * 16) ^ ((r & 7) << 4);
        *(uint4*)((char*)lsa + byte) = v;
    }
    __syncthreads();

    const unsigned short* w0 = wbt + (size_t)(wid * 32 + lrow) * KDIM + lg * 8;

    f32x4 acc[2][2] = {};
    bf16x8 br0[8][2], br1[8][2];

#pragma unroll
    for (int tt = 0; tt < 8; tt++)
#pragma unroll
        for (int ni = 0; ni < 2; ni++)
            br0[tt][ni] = *(const bf16x8*)(w0 + ni * 16 * KDIM + tt * 32);
    __builtin_amdgcn_sched_barrier(0);

#pragma unroll
    for (int k = 0; k < Kc; k++) {
        if (k < Kc - 1) {
#pragma unroll
            for (int tt = 0; tt < 8; tt++)
#pragma unroll
                for (int ni = 0; ni < 2; ni++) {
                    bf16x8 v = *(const bf16x8*)(w0 + ni * 16 * KDIM + (k + 1) * 256 + tt * 32);
                    if (k & 1) br0[tt][ni] = v; else br1[tt][ni] = v;
                }
            __builtin_amdgcn_sched_barrier(0);
        }
#pragma unroll
        for (int tt = 0; tt < 8; tt++) {
            bf16x8 a[2];
#pragma unroll
            for (int mi = 0; mi < 2; mi++) {
                int l = mi * 16 + lrow + k;
                a[mi] = *(const bf16x8*)((const char*)lsa + l * 512
                        + ((lg * 16 + tt * 64) ^ ((l & 7) << 4)));
            }
#pragma unroll
            for (int mi = 0; mi < 2; mi++)
#pragma unroll
                for (int ni = 0; ni < 2; ni++) {
                    bf16x8 bv = (k & 1) ? br1[tt][ni] : br0[tt][ni];
                    acc[mi][ni] = __builtin_amdgcn_mfma_f32_16x16x32_bf16(
                        a[mi], bv, acc[mi][ni], 0, 0, 0);
                }
        }
    }

    // epilogue: relu(acc+bias) -> shs (f32), all 32 rows
#pragma unroll
    for (int mi = 0; mi < 2; mi++) {
        int rrow = mi * 16 + lg * 4;
#pragma unroll
        for (int ni = 0; ni < 2; ni++) {
            int co = wid * 32 + ni * 16 + lrow;
            float bias = cb[co];
#pragma unroll
            for (int r = 0; r < 4; r++)
                shs[rrow + r][co] = fmaxf(acc[mi][ni][r] + bias, 0.0f);
        }
    }
    __syncthreads();

    // final: 8 waves x 4 rows — ortho + link + disc
#pragma unroll
    for (int rr = 0; rr < 4; rr++) {
        int row = wid * 4 + rr;          // 0..31
        int b = b0 + row;
        int lr = row + 3;
        int swz = (lr & 7) << 4;
        float lsv[4], shv[4];
        float dot = 0.f, nrm = 0.f;
#pragma unroll
        for (int i = 0; i < 4; i++) {
            int ci = lane + i * 64;
            lsv[i] = bf2f(*(const unsigned short*)((const char*)lsa + lr * 512 + ((ci * 2) ^ swz)));
            shv[i] = shs[row][ci];
            dot += lsv[i] * shv[i];
            nrm += shv[i] * shv[i];
        }
        for (int m = 32; m; m >>= 1) { dot += __shfl_xor(dot, m); nrm += __shfl_xor(nrm, m); }
        float coef = dot / (nrm + 1e-12f);
        float p0 = 0.f, p1 = 0.f, d0 = 0.f, d1 = 0.f, d2 = 0.f, d3 = 0.f;
#pragma unroll
        for (int i = 0; i < 4; i++) {
            int ci = lane + i * 64;
            float e = lsv[i] - coef * shv[i] + shv[i];
            p0 += e * link_w[ci * 2];
            p1 += e * link_w[ci * 2 + 1];
            d0 += shv[i] * lc_w[ci * 4];
            d1 += shv[i] * lc_w[ci * 4 + 1];
            d2 += shv[i] * lc_w[ci * 4 + 2];
            d3 += shv[i] * lc_w[ci * 4 + 3];
        }
        for (int m = 32; m; m >>= 1) {
            p0 += __shfl_xor(p0, m); p1 += __shfl_xor(p1, m);
            d0 += __shfl_xor(d0, m); d1 += __shfl_xor(d1, m);
            d2 += __shfl_xor(d2, m); d3 += __shfl_xor(d3, m);
        }
        if (lane == 0) {
            out[b * 2]     = p0 + link_b[0];
            out[b * 2 + 1] = p1 + link_b[1];
            float* dd = out + 2 * Bc;
            dd[b * 4]     = d0 + lc_b[0];
            dd[b * 4 + 1] = d1 + lc_b[1];
            dd[b * 4 + 2] = d2 + lc_b[2];
            dd[b * 4 + 3] = d3 + lc_b[3];
        }
    }
}

// ---------------- launch ----------------

extern "C" void kernel_launch(void* const* d_in, const int* in_sizes, int n_in,
                              void* d_out, int out_size, void* d_ws, size_t ws_size,
                              hipStream_t stream) {
    const float* x_nodes    = (const float*)d_in[0];
    const int*   edge_index = (const int*)d_in[1];
    const float* W1   = (const float*)d_in[2];
    // d_in[3] = b1 (cancels in BN)
    const float* gamma = (const float*)d_in[4];
    const float* beta  = (const float*)d_in[5];
    const float* W2   = (const float*)d_in[6];
    const float* b2   = (const float*)d_in[7];
    const float* conv_w = (const float*)d_in[8];
    const float* conv_b = (const float*)d_in[9];
    const float* lc_w   = (const float*)d_in[10];
    const float* lc_b   = (const float*)d_in[11];
    const float* link_w = (const float*)d_in[12];
    const float* link_b = (const float*)d_in[13];
    const int* now = (const int*)d_in[14];
    const int* ln  = (const int*)d_in[15];
    const int* rn  = (const int*)d_in[16];
    float* out = (float*)d_out;

    char* base = (char*)d_ws;
    size_t off = 0;
    auto carve = [&](size_t bytes) {
        void* p = base + off;
        off = (off + bytes + 255) & ~(size_t)255;
        return p;
    };
    // zero-init region: bitmap .. stats (zeroed inside k_prep)
    unsigned* bitmap = (unsigned*)carve(6272 * 4);
    int*      gcnt   = (int*)carve(4 * 4);
    int*      gcur   = (int*)carve(4 * 4);
    double*   stats  = (double*)carve(8 * 8);
    // rest (no zeroing needed)
    int*    blkCnt   = (int*)carve((size_t)Lc * FBLK * FB * 4);
    int*    binned   = (int*)carve((size_t)Lc * FBLK * FB * SCAP * 4);
    int*    rstart   = (int*)carve((size_t)Mtot * 4);
    int*    cnt      = (int*)carve((size_t)Mtot * 4);
    int*    csr      = (int*)carve((size_t)NBINS * CAPc * 4);
    float*  dis      = (float*)carve((size_t)Mtot * 4);
    float*  g        = (float*)carve((size_t)Mtot * 4);
    float2* ns       = (float2*)carve((size_t)Mtot * 8);
    float*  cbuf     = (float*)carve(Lc * 72 * 4);
    int*    ord      = (int*)carve((size_t)PADTOT * 4);
    unsigned short* acch = (unsigned short*)carve((size_t)PADTOT * 64 * 2);
    unsigned short* lsh  = (unsigned short*)carve((size_t)Bc * 256 * 2);
    unsigned short* wbt  = (unsigned short*)carve((size_t)EDc * KDIM * 2);
    unsigned short* w2t  = (unsigned short*)carve((size_t)Lc * 128 * 64 * 2);
    (void)ws_size;

    int zn = (int)(((char*)(stats + 8) - (char*)bitmap) / 4);

    k_prep<<<1920, 256, 0, stream>>>(conv_w, wbt, W2, w2t, (int*)bitmap, zn);
    k_mark<<<64, 256, 0, stream>>>(now, ln, rn, ord, bitmap, gcnt);
    k_binfill<<<dim3(FBLK, Lc), 512, 0, stream>>>(edge_index, blkCnt, binned);
    k_csr<<<NBINS, 512, 0, stream>>>(blkCnt, binned, x_nodes, bitmap,
                                     csr, rstart, cnt, dis, g);
    k_s_bin<<<NBINS, 512, 0, stream>>>(blkCnt, binned, g, dis, ns, stats);
    k_ordcvec<<<65, 256, 0, stream>>>(now, gcnt, gcur, ord, stats, W1, gamma, cbuf);
    k_agg<<<PADTOT / 4, 256, 0, stream>>>(ord, ln, rn, rstart, cnt, csr, ns,
                                          cbuf, beta, acch);
    k_embgemm<<<PADTOT / 16, 256, 0, stream>>>(acch, ord, w2t, b2, lsh);
    k_convfinal<<<Bc / 32, 512, 0, stream>>>(lsh, wbt, conv_b,
                                             lc_w, lc_b, link_w, link_b, out);
}

// Round 19
// 178.903 us; speedup vs baseline: 1.3211x; 1.3211x over previous
//
#include <hip/hip_runtime.h>
#include <hip/hip_bf16.h>

#define Lc 4
#define Nc 50000
#define Ec 800000
#define Bc 16384
#define EDc 256
#define Kc 7
#define Mtot (Lc * Nc)      // 200000 nodes total
#define KDIM (EDc * Kc)     // 1792

#define BINW 512            // nodes per bin
#define BSH 9
#define FB 98               // bins per layer = ceil(50000/512)
#define NBINS (FB * Lc)     // 392
#define CAPc 12288          // fixed bin capacity (mean 8192)
#define CHUNK 8192          // edges per binfill block (long write runs!)
#define FBLK ((Ec + CHUNK - 1) / CHUNK)  // 98

#define PADTOT 33024        // 32768 sides + per-layer pad to 64
#define PADBIT (1 << 24)

typedef __attribute__((ext_vector_type(8))) short bf16x8;
typedef __attribute__((ext_vector_type(4))) float f32x4;

static __device__ __forceinline__ unsigned short f2bf(float f) {
    unsigned u = __float_as_uint(f);
    unsigned r = (u + 0x7fffu + ((u >> 16) & 1u)) >> 16;
    return (unsigned short)r;
}
static __device__ __forceinline__ float bf2f(unsigned short u) {
    return __uint_as_float(((unsigned)u) << 16);
}

// ---------------- binned edge sort (fixed-capacity bins) ----------------

__global__ __launch_bounds__(1024) void k_binfill(const int* __restrict__ ei,
                                                  int* __restrict__ binCursor,
                                                  int* __restrict__ binned) {
    int l = blockIdx.y;
    int e0 = blockIdx.x * CHUNK;
    __shared__ int lh[FB], lcur[FB];
    if (threadIdx.x < FB) lh[threadIdx.x] = 0;
    __syncthreads();
    const int* srcp = ei + (size_t)l * 2 * Ec;
    const int* dstp = srcp + Ec;
#pragma unroll
    for (int it = 0; it < CHUNK / 1024; it++) {
        int idx = e0 + it * 1024 + threadIdx.x;
        if (idx < Ec) atomicAdd(&lh[dstp[idx] >> BSH], 1);
    }
    __syncthreads();
    if (threadIdx.x < FB) {
        int c = lh[threadIdx.x];
        int bin = l * FB + threadIdx.x;
        int st = c ? atomicAdd(&binCursor[bin], c) : 0;
        lcur[threadIdx.x] = bin * CAPc + min(st, CAPc);
        lh[threadIdx.x] = bin * CAPc + CAPc;    // reuse as limit
    }
    __syncthreads();
#pragma unroll
    for (int it = 0; it < CHUNK / 1024; it++) {
        int idx = e0 + it * 1024 + threadIdx.x;
        if (idx < Ec) {
            int d = dstp[idx], sv = srcp[idx];
            int t = d >> BSH;
            int pos = atomicAdd(&lcur[t], 1);
            if (pos < lh[t]) binned[pos] = (sv << BSH) | (d & (BINW - 1));
        }
    }
}

// mark sampled (layer,node) bitmap + per-layer sample counts + init ord
__global__ void k_mark(const int* __restrict__ now, const int* __restrict__ lnn,
                       const int* __restrict__ rnn, int* __restrict__ ord,
                       unsigned* __restrict__ bitmap, int* __restrict__ gcnt) {
    int b = blockIdx.x * 256 + threadIdx.x;   // exactly 16384 threads
    for (int p = b; p < PADTOT; p += 16384) ord[p] = PADBIT;
    int l = now[b];
    int a1 = l * Nc + lnn[b];
    atomicOr(&bitmap[a1 >> 5], 1u << (a1 & 31));
    int a2 = l * Nc + rnn[b];
    atomicOr(&bitmap[a2 >> 5], 1u << (a2 & 31));
    int lane = threadIdx.x & 63;
#pragma unroll
    for (int ll = 0; ll < 4; ll++) {
        unsigned long long m = __ballot(l == ll);
        if (m && lane == __builtin_ctzll(m)) atomicAdd(&gcnt[ll], __popcll(m));
    }
}

// scatter sides into layer-sorted, 64-padded order
__global__ void k_order2(const int* __restrict__ now, const int* __restrict__ gcnt,
                         int* __restrict__ gcur, int* __restrict__ ord) {
    int b = blockIdx.x * 256 + threadIdx.x;   // exactly 16384
    int l = now[b];
    int segBase = 0;
    for (int ll = 0; ll < l; ll++) segBase += (2 * gcnt[ll] + 63) & ~63;
    int lane = threadIdx.x & 63;
#pragma unroll
    for (int ll = 0; ll < 4; ll++) {
        unsigned long long m = __ballot(l == ll);
        if (!m) continue;
        int ldr = __builtin_ctzll(m);
        int bs = 0;
        if (lane == ldr) bs = atomicAdd(&gcur[ll], __popcll(m));
        bs = __shfl(bs, ldr);
        if (l == ll) {
            int rk = __popcll(m & (lane ? ((1ull << lane) - 1) : 0ull));
            int sp = segBase + 2 * (bs + rk);
            ord[sp] = (2 * b) | (ll << 20);
            ord[sp + 1] = (2 * b + 1) | (ll << 20);
        }
    }
}

// one block per bin: hist + rstart/cnt/dis/g + bitmap-filtered csr scatter
__global__ __launch_bounds__(512) void k_csr(const int* __restrict__ binCnt,
                                             const int* __restrict__ binned,
                                             const float* __restrict__ x_nodes,
                                             const unsigned* __restrict__ bitmap,
                                             int* __restrict__ csr,
                                             int* __restrict__ rstart,
                                             int* __restrict__ cnt,
                                             float* __restrict__ dis,
                                             float* __restrict__ g) {
    int b = blockIdx.x;              // 0..NBINS-1
    int l = b / FB, gg = b % FB;
    int rs = b * CAPc;
    int cntb = binCnt[b];
    if (cntb > CAPc) cntb = CAPc;
    int re = rs + cntb;
    __shared__ int hist[BINW];
    hist[threadIdx.x] = 0;
    __syncthreads();
    for (int i = rs + threadIdx.x; i < re; i += 512)
        atomicAdd(&hist[binned[i] & (BINW - 1)], 1);
    __syncthreads();
    int lane = threadIdx.x & 63, wid = threadIdx.x >> 6;
    int v = hist[threadIdx.x];
    int x = v;
#pragma unroll
    for (int off = 1; off < 64; off <<= 1) {
        int y = __shfl_up(x, off);
        if (lane >= off) x += y;
    }
    __shared__ int ws[8];
    if (lane == 63) ws[wid] = x;
    __syncthreads();
    int carry = 0;
    for (int w = 0; w < wid; w++) carry += ws[w];
    int exc = x - v + carry;         // exclusive prefix within bin
    int n = gg * BINW + threadIdx.x;
    int n4 = l * Nc + n;
    if (n < Nc) {
        rstart[n4] = rs + exc;
        cnt[n4] = v;
        float dn = rsqrtf((float)v + 1.0f);   // +1 self loop
        dis[n4] = dn;
        g[n4] = dn * x_nodes[(size_t)l * Nc + n];
    }
    __syncthreads();                 // all reads of hist done
    hist[threadIdx.x] = rs + exc;    // reuse as cursor
    __syncthreads();
    int lbase = l * Nc + gg * BINW;
    for (int i = rs + threadIdx.x; i < re; i += 512) {
        unsigned p = (unsigned)binned[i];
        int d = p & (BINW - 1);
        int nn4 = lbase + d;
        if ((bitmap[nn4 >> 5] >> (nn4 & 31)) & 1u) {   // only sampled dst rows
            int pos = atomicAdd(&hist[d], 1);
            csr[pos] = (int)(p >> BSH);
        }
    }
}

// edge-parallel s aggregation + BN stats (per bin); packs ns = (dis, s)
__global__ __launch_bounds__(512) void k_s_bin(const int* __restrict__ binCnt,
                                               const int* __restrict__ binned,
                                               const float* __restrict__ g,
                                               const float* __restrict__ dis,
                                               float2* __restrict__ ns,
                                               double* __restrict__ stats) {
    int b = blockIdx.x;              // 0..NBINS-1
    int l = b / FB, gg = b % FB;
    int rs = b * CAPc;
    int cntb = binCnt[b];
    if (cntb > CAPc) cntb = CAPc;
    int re = rs + cntb;
    const float* gl = g + (size_t)l * Nc;
    __shared__ float acc[BINW];
    acc[threadIdx.x] = 0.f;
    __syncthreads();
    for (int i = rs + threadIdx.x; i < re; i += 512) {
        unsigned p = (unsigned)binned[i];
        atomicAdd(&acc[p & (BINW - 1)], gl[p >> BSH]);   // LDS fp32 atomic
    }
    __syncthreads();
    int n = gg * BINW + threadIdx.x;
    int n4 = l * Nc + n;
    double v = 0.0, v2 = 0.0;
    if (n < Nc) {
        float dn = dis[n4];
        float sf = dn * (acc[threadIdx.x] + g[n4]);  // neighbors + self loop
        ns[n4] = make_float2(dn, sf);
        v = (double)sf;
        v2 = (double)sf * (double)sf;
    }
    for (int m = 32; m; m >>= 1) { v += __shfl_xor(v, m); v2 += __shfl_xor(v2, m); }
    __shared__ double r0[8], r1[8];
    int wid = threadIdx.x >> 6, lane = threadIdx.x & 63;
    if (lane == 0) { r0[wid] = v; r1[wid] = v2; }
    __syncthreads();
    if (threadIdx.x == 0) {
        double a = 0, bb = 0;
        for (int w = 0; w < 8; w++) { a += r0[w]; bb += r1[w]; }
        atomicAdd(&stats[l * 2 + 0], a);
        atomicAdd(&stats[l * 2 + 1], bb);
    }
}

__global__ void k_cvec4(const double* __restrict__ stats, const float* __restrict__ W1,
                        const float* __restrict__ gamma, float* __restrict__ cbuf) {
    int l = threadIdx.x >> 6, h = threadIdx.x & 63;  // 256 threads
    double mean = stats[l * 2] / (double)Nc;
    double var = stats[l * 2 + 1] / (double)Nc - mean * mean;
    float w = W1[l * 64 + h];
    cbuf[l * 72 + h] = gamma[l * 64 + h] * w * rsqrtf((float)var * w * w + 1e-5f);
    if (h == 0) cbuf[l * 72 + 64] = (float)mean;
}

// ---------------- per-side aggregation (lane-parallel edge gather) ---------

__global__ __launch_bounds__(256) void k_agg(const int* __restrict__ ord,
        const int* __restrict__ lnn, const int* __restrict__ rnn,
        const int* __restrict__ rstart, const int* __restrict__ cnt,
        const int* __restrict__ csr, const float2* __restrict__ ns,
        const float* __restrict__ cbuf, const float* __restrict__ beta,
        unsigned short* __restrict__ acch) {
    int pos = blockIdx.x * 4 + (threadIdx.x >> 6);
    int lane = threadIdx.x & 63;
    int ordv = ord[pos];
    if (ordv & PADBIT) { acch[(size_t)pos * 64 + lane] = 0; return; }
    int side = ordv & 0xFFFFF;
    int l = (ordv >> 20) & 3;
    int b = side >> 1;
    int n = (side & 1) ? rnn[b] : lnn[b];
    int n4 = l * Nc + n;
    float c = cbuf[l * 72 + lane], mu = cbuf[l * 72 + 64], bt = beta[l * 64 + lane];
    const float2* nsl = ns + (size_t)l * Nc;
    int st = rstart[n4], deg = cnt[n4];
    float a = 0.f;
    for (int base = 0; base < deg; base += 64) {
        int e = base + lane;
        int sv = (e < deg) ? csr[st + e] : 0;        // coalesced vector load
        float nv = 0.f, fv = 0.f;
        if (e < deg) {
            float2 nf = nsl[sv];                     // 64 parallel gathers
            nv = nf.x; fv = nf.y;
        }
        int m = min(64, deg - base);
        for (int j = 0; j < m; j++) {
            float nj = __shfl(nv, j);
            float fj = __shfl(fv, j);
            a += nj * fmaxf(c * (fj - mu) + bt, 0.f);
        }
    }
    float2 nself = ns[n4];
    float hs = fmaxf(c * (nself.y - mu) + bt, 0.f);
    a = nself.x * a + nself.x * nself.x * hs;
    acch[(size_t)pos * 64 + lane] = f2bf(a);
}

// batched MFMA GEMM: [PADTOT x 64] @ W2[l][64 x 128] -> lsh (bf16)
__global__ __launch_bounds__(256) void k_embgemm(const unsigned short* __restrict__ acch,
        const int* __restrict__ ord, const unsigned short* __restrict__ w2t,
        const float* __restrict__ b2, unsigned short* __restrict__ lsh) {
    int t0 = blockIdx.x * 16;
    int wn = threadIdx.x >> 6, lane = threadIdx.x & 63;
    int lrow = lane & 15, lg = lane >> 4;
    int l = (ord[t0] >> 20) & 3;     // uniform layer for all valid rows in tile
    const unsigned short* ap = acch + (size_t)(t0 + lrow) * 64 + lg * 8;
    const unsigned short* bp = w2t + (size_t)(l * 128 + wn * 32 + lrow) * 64 + lg * 8;
    f32x4 acc[2] = {};
#pragma unroll
    for (int kt = 0; kt < 2; kt++) {
        bf16x8 a = *(const bf16x8*)(ap + kt * 32);
        bf16x8 b0 = *(const bf16x8*)(bp + kt * 32);
        bf16x8 b1 = *(const bf16x8*)(bp + 16 * 64 + kt * 32);
        acc[0] = __builtin_amdgcn_mfma_f32_16x16x32_bf16(a, b0, acc[0], 0, 0, 0);
        acc[1] = __builtin_amdgcn_mfma_f32_16x16x32_bf16(a, b1, acc[1], 0, 0, 0);
    }
#pragma unroll
    for (int r = 0; r < 4; r++) {
        int pos = t0 + lg * 4 + r;
        int ordv = ord[pos];
        if (ordv & PADBIT) continue;
        int side = ordv & 0xFFFFF;
        size_t base = (size_t)(side >> 1) * 256 + (side & 1) * 128;
#pragma unroll
        for (int ni = 0; ni < 2; ni++) {
            int n = wn * 32 + ni * 16 + lrow;
            lsh[base + n] = f2bf(acc[ni][r] + b2[l * 128 + n]);
        }
    }
}

// ---------------- tail kernels ----------------

// conv_w [co][ci][k] fp32 -> wbt [co][k*256+ci] bf16 (B^T layout for MFMA)
__global__ void k_wbf(const float* __restrict__ w, unsigned short* __restrict__ wbt) {
    int i = blockIdx.x * 256 + threadIdx.x; // 458752
    int co = i / KDIM;
    int r = i % KDIM;
    int ci = r / Kc, k = r % Kc;
    wbt[(size_t)co * KDIM + k * EDc + ci] = f2bf(w[i]);
}

// W2 [l][h][d] fp32 -> w2t [l][d][h] bf16; ALSO zeroes the scratch region
// (binCursor/gcnt/gcur/bitmap/stats) — replaces hipMemsetAsync, whose
// fillBufferAligned dispatch cost ~40us/replay (round-12 profile).
__global__ void k_w2t(const float* __restrict__ W2, unsigned short* __restrict__ w2t,
                      int* __restrict__ zeroRegion, int zn) {
    int i = blockIdx.x * 256 + threadIdx.x; // 32768
    if (i < zn) zeroRegion[i] = 0;
    int l = i >> 13, r = i & 8191;
    int d = r >> 6, h = r & 63;
    w2t[i] = f2bf(W2[(size_t)(l * 64 + h) * 128 + d]);
}

// conv1d as bf16 MFMA GEMM (round-8 structure: M-tile 64, 256 blocks,
// B register-double-buffered from global; 5 restructure attempts
// (rounds 14-18) all regressed — this form is the local optimum).
__global__ __launch_bounds__(512, 1) void k_convmma(const unsigned short* __restrict__ lsh,
                                                    const unsigned short* __restrict__ wbt,
                                                    const float* __restrict__ cb,
                                                    float* __restrict__ sh) {
    __shared__ unsigned short lsa[70 * EDc];   // 35840 B
    int b0 = blockIdx.x * 64;
    int wid = threadIdx.x >> 6, lane = threadIdx.x & 63;
    int lrow = lane & 15, lg = lane >> 4;

    for (int idx = threadIdx.x; idx < 70 * 32; idx += 512) {
        int r = idx >> 5, c = idx & 31;
        int grow = b0 - 3 + r;
        uint4 v = make_uint4(0u, 0u, 0u, 0u);
        if ((unsigned)grow < (unsigned)Bc)
            v = *(const uint4*)(lsh + (size_t)grow * EDc + c * 8);
        int byte = (r * 512 + c * 16) ^ ((r & 7) << 4);
        *(uint4*)((char*)lsa + byte) = v;
    }
    __syncthreads();

    const unsigned short* w0 = wbt + (size_t)(wid * 32 + lrow) * KDIM + lg * 8;

    f32x4 acc[4][2] = {};
    bf16x8 br0[8][2], br1[8][2];

#pragma unroll
    for (int tt = 0; tt < 8; tt++)
#pragma unroll
        for (int ni = 0; ni < 2; ni++)
            br0[tt][ni] = *(const bf16x8*)(w0 + ni * 16 * KDIM + tt * 32);

#pragma unroll
    for (int k = 0; k < Kc; k++) {
        if (k < Kc - 1) {
#pragma unroll
            for (int tt = 0; tt < 8; tt++)
#pragma unroll
                for (int ni = 0; ni < 2; ni++) {
                    bf16x8 v = *(const bf16x8*)(w0 + ni * 16 * KDIM + (k + 1) * 256 + tt * 32);
                    if (k & 1) br0[tt][ni] = v; else br1[tt][ni] = v;
                }
        }
#pragma unroll
        for (int tt = 0; tt < 8; tt++) {
            bf16x8 a[4];
#pragma unroll
            for (int mi = 0; mi < 4; mi++) {
                int l = mi * 16 + lrow + k;
                a[mi] = *(const bf16x8*)((const char*)lsa + l * 512
                        + ((lg * 16 + tt * 64) ^ ((l & 7) << 4)));
            }
#pragma unroll
            for (int mi = 0; mi < 4; mi++)
#pragma unroll
                for (int ni = 0; ni < 2; ni++) {
                    bf16x8 bv = (k & 1) ? br1[tt][ni] : br0[tt][ni];
                    acc[mi][ni] = __builtin_amdgcn_mfma_f32_16x16x32_bf16(
                        a[mi], bv, acc[mi][ni], 0, 0, 0);
                }
        }
    }

#pragma unroll
    for (int mi = 0; mi < 4; mi++) {
        int rbase = b0 + mi * 16 + lg * 4;
#pragma unroll
        for (int ni = 0; ni < 2; ni++) {
            int co = wid * 32 + ni * 16 + lrow;
            float bias = cb[co];
#pragma unroll
            for (int r = 0; r < 4; r++)
                sh[(size_t)(rbase + r) * EDc + co] = fmaxf(acc[mi][ni][r] + bias, 0.0f);
        }
    }
}

// 4 samples per 256-thread block (wave = one sample)
__global__ __launch_bounds__(256) void k_final(const unsigned short* __restrict__ lsh,
                        const float* __restrict__ sh,
                        const float* __restrict__ lc_w, const float* __restrict__ lc_b,
                        const float* __restrict__ link_w, const float* __restrict__ link_b,
                        float* __restrict__ out) {
    int b = blockIdx.x * 4 + (threadIdx.x >> 6);
    int lane = threadIdx.x & 63;
    float lsv[4], shv[4];
    float dot = 0.f, nrm = 0.f;
#pragma unroll
    for (int i = 0; i < 4; i++) {
        int ci = lane + i * 64;
        lsv[i] = bf2f(lsh[(size_t)b * 256 + ci]);
        shv[i] = sh[(size_t)b * 256 + ci];
        dot += lsv[i] * shv[i];
        nrm += shv[i] * shv[i];
    }
    for (int m = 32; m; m >>= 1) { dot += __shfl_xor(dot, m); nrm += __shfl_xor(nrm, m); }
    float coef = dot / (nrm + 1e-12f);
    float p0 = 0.f, p1 = 0.f, d0 = 0.f, d1 = 0.f, d2 = 0.f, d3 = 0.f;
#pragma unroll
    for (int i = 0; i < 4; i++) {
        int ci = lane + i * 64;
        float e = lsv[i] - coef * shv[i] + shv[i];
        p0 += e * link_w[ci * 2];
        p1 += e * link_w[ci * 2 + 1];
        d0 += shv[i] * lc_w[ci * 4];
        d1 += shv[i] * lc_w[ci * 4 + 1];
        d2 += shv[i] * lc_w[ci * 4 + 2];
        d3 += shv[i] * lc_w[ci * 4 + 3];
    }
    for (int m = 32; m; m >>= 1) {
        p0 += __shfl_xor(p0, m); p1 += __shfl_xor(p1, m);
        d0 += __shfl_xor(d0, m); d1 += __shfl_xor(d1, m);
        d2 += __shfl_xor(d2, m); d3 += __shfl_xor(d3, m);
    }
    if (lane == 0) {
        out[b * 2]     = p0 + link_b[0];
        out[b * 2 + 1] = p1 + link_b[1];
        float* dd = out + 2 * Bc;
        dd[b * 4]     = d0 + lc_b[0];
        dd[b * 4 + 1] = d1 + lc_b[1];
        dd[b * 4 + 2] = d2 + lc_b[2];
        dd[b * 4 + 3] = d3 + lc_b[3];
    }
}

// ---------------- launch ----------------

extern "C" void kernel_launch(void* const* d_in, const int* in_sizes, int n_in,
                              void* d_out, int out_size, void* d_ws, size_t ws_size,
                              hipStream_t stream) {
    const float* x_nodes    = (const float*)d_in[0];
    const int*   edge_index = (const int*)d_in[1];
    const float* W1   = (const float*)d_in[2];
    // d_in[3] = b1 (cancels in BN)
    const float* gamma = (const float*)d_in[4];
    const float* beta  = (const float*)d_in[5];
    const float* W2   = (const float*)d_in[6];
    const float* b2   = (const float*)d_in[7];
    const float* conv_w = (const float*)d_in[8];
    const float* conv_b = (const float*)d_in[9];
    const float* lc_w   = (const float*)d_in[10];
    const float* lc_b   = (const float*)d_in[11];
    const float* link_w = (const float*)d_in[12];
    const float* link_b = (const float*)d_in[13];
    const int* now = (const int*)d_in[14];
    const int* ln  = (const int*)d_in[15];
    const int* rn  = (const int*)d_in[16];
    float* out = (float*)d_out;

    char* base = (char*)d_ws;
    size_t off = 0;
    auto carve = [&](size_t bytes) {
        void* p = base + off;
        off = (off + bytes + 255) & ~(size_t)255;
        return p;
    };
    // zero-init region: binCursor .. stats (zeroed inside k_w2t)
    int*      binCursor = (int*)carve(NBINS * 4);
    int*      gcnt      = (int*)carve(4 * 4);
    int*      gcur      = (int*)carve(4 * 4);
    unsigned* bitmap    = (unsigned*)carve(6272 * 4);
    double*   stats     = (double*)carve(8 * 8);
    // rest
    int*    binned    = (int*)carve((size_t)NBINS * CAPc * 4);
    int*    rstart    = (int*)carve((size_t)Mtot * 4);
    int*    cnt       = (int*)carve((size_t)Mtot * 4);
    int*    csr       = (int*)carve((size_t)NBINS * CAPc * 4);
    float*  dis       = (float*)carve((size_t)Mtot * 4);
    float*  g         = (float*)carve((size_t)Mtot * 4);
    float2* ns        = (float2*)carve((size_t)Mtot * 8);
    float*  cbuf      = (float*)carve(Lc * 72 * 4);
    int*    ord       = (int*)carve((size_t)PADTOT * 4);
    unsigned short* acch = (unsigned short*)carve((size_t)PADTOT * 64 * 2);
    float*  shb       = (float*)carve((size_t)Bc * 256 * 4);
    unsigned short* lsh = (unsigned short*)carve((size_t)Bc * 256 * 2);
    unsigned short* wbt = (unsigned short*)carve((size_t)EDc * KDIM * 2);
    unsigned short* w2t = (unsigned short*)carve((size_t)Lc * 128 * 64 * 2);
    (void)ws_size;

    int zn = (int)(((char*)(stats + 8) - (char*)binCursor) / 4);

    k_w2t<<<128, 256, 0, stream>>>(W2, w2t, binCursor, zn);   // also zeroes scratch
    k_wbf<<<1792, 256, 0, stream>>>(conv_w, wbt);
    k_mark<<<64, 256, 0, stream>>>(now, ln, rn, ord, bitmap, gcnt);

    k_binfill<<<dim3(FBLK, Lc), 1024, 0, stream>>>(edge_index, binCursor, binned);
    k_csr<<<NBINS, 512, 0, stream>>>(binCursor, binned, x_nodes, bitmap,
                                     csr, rstart, cnt, dis, g);
    k_s_bin<<<NBINS, 512, 0, stream>>>(binCursor, binned, g, dis, ns, stats);
    k_cvec4<<<1, 256, 0, stream>>>(stats, W1, gamma, cbuf);
    k_order2<<<64, 256, 0, stream>>>(now, gcnt, gcur, ord);
    k_agg<<<PADTOT / 4, 256, 0, stream>>>(ord, ln, rn, rstart, cnt, csr, ns,
                                          cbuf, beta, acch);
    k_embgemm<<<PADTOT / 16, 256, 0, stream>>>(acch, ord, w2t, b2, lsh);

    k_convmma<<<Bc / 64, 512, 0, stream>>>(lsh, wbt, conv_b, shb);
    k_final<<<Bc / 4, 256, 0, stream>>>(lsh, shb, lc_w, lc_b, link_w, link_b, out);
}